// Round 11
// baseline (694.653 us; speedup 1.0000x reference)
//
#include <hip/hip_runtime.h>
#include <hip/hip_bf16.h>

#define T_SEQ  180
#define LATENT 128
#define HIDDEN 256

typedef __attribute__((ext_vector_type(8)))  short  short8;    // 8 x bf16 (4 VGPRs)
typedef __attribute__((ext_vector_type(4)))  float  floatx4;   // 16x16 MFMA acc
typedef __attribute__((ext_vector_type(16))) float  floatx16;  // 32x32 MFMA acc

// ---- d_ws layout (ushort units) ----
// [0, 196608)      : w_hh 32x32x16 B-frags: frag=(w*3+g)*16+kc, 512 ushorts each
// [196608, 229376) : fc_w 32x32x16 B-frags: frag=w*8+kc
#define WHH_US 196608

// ---- dynamic LDS layout (bytes) ----
// [0,      131072) : w_hh n-gate (g=2) frags: (wv*16+kc)*1024 B
// [131072, 147968) : h_lds 32 rows x 264 ushorts
// [147968, 152064) : obufw [2][8][32][2] float (ping-pong proj partials)
#define HLDS_OFF   131072
#define OBUF_OFF   147968
#define SMEM_BYTES 152064

__device__ __forceinline__ unsigned short f2bf(float f) {
    unsigned int u = __float_as_uint(f);
    u += 0x7fffu + ((u >> 16) & 1u);      // round-to-nearest-even
    return (unsigned short)(u >> 16);
}

__device__ __forceinline__ float sigmoid_fast(float x) {
    return __builtin_amdgcn_rcpf(1.0f + __expf(-x));
}
__device__ __forceinline__ float tanh_fast(float x) {
    // tanh(x) = 1 - 2/(e^{2x}+1); overflow-safe (e^inf -> inf -> rcp -> 0)
    return 1.0f - 2.0f * __builtin_amdgcn_rcpf(1.0f + __expf(2.0f * x));
}

// Pack w_hh [768,256] fp32 row-major -> bf16 32x32x16 B-fragments.
// B[k][n]: n = lane&31, k = kc*16 + (lane>>5)*8 + j (j=0..7 consecutive).
__global__ void pack_whh(const float* __restrict__ whh, unsigned short* __restrict__ dst) {
    int tid  = blockIdx.x * blockDim.x + threadIdx.x;  // 24576 threads
    int lane = tid & 63;
    int frag = tid >> 6;                               // 0..383
    int kc   = frag & 15;
    int g    = (frag >> 4) % 3;
    int w    = frag / 48;
    int col  = w * 32 + (lane & 31);
    int jout = g * 256 + col;                          // row of w_hh
    int k0   = kc * 16 + ((lane >> 5) << 3);
    const float* src = whh + jout * 256 + k0;          // 8 consecutive k
    unsigned int u[4];
#pragma unroll
    for (int j = 0; j < 4; ++j)
        u[j] = (unsigned int)f2bf(src[2 * j]) | ((unsigned int)f2bf(src[2 * j + 1]) << 16);
    *(uint4*)(dst + frag * 512 + lane * 8) = make_uint4(u[0], u[1], u[2], u[3]);
}

// Pack fc_w [256,128] fp32 row-major -> bf16 32x32x16 B-fragments (K=128, kc 0..7).
__global__ void pack_fcw(const float* __restrict__ fcw, unsigned short* __restrict__ dst) {
    int tid  = blockIdx.x * blockDim.x + threadIdx.x;  // 4096 threads
    int lane = tid & 63;
    int frag = tid >> 6;                               // 0..63
    int kc   = frag & 7;
    int w    = frag >> 3;
    int col  = w * 32 + (lane & 31);
    int k0   = kc * 16 + ((lane >> 5) << 3);
    const float* src = fcw + col * 128 + k0;
    unsigned int u[4];
#pragma unroll
    for (int j = 0; j < 4; ++j)
        u[j] = (unsigned int)f2bf(src[2 * j]) | ((unsigned int)f2bf(src[2 * j + 1]) << 16);
    *(uint4*)(dst + frag * 512 + lane * 8) = make_uint4(u[0], u[1], u[2], u[3]);
}

// Persistent GRU: 256 blocks x 512 threads, 32 rows/block, wave owns 32 cols.
// r11 MONOLITHIC 32x32x16: one 32-row step, 48 MFMA/wave (3 gates x 16 kc) at
// the higher 32x32 rate; n-gate LDS frags read ONCE per step (2-slot structure
// read them twice). r7-r10 falsified all MFMA/VALU overlap tricks -> demand
// reduction is the gradient. Register law (r4/r5): 32 weight frags = 128 regs
// max in registers; total <= 256 unified incl AGPRs.
__global__ __launch_bounds__(512, 2) void gru_main(
    const float* __restrict__ z,
    const float* __restrict__ fc_b,
    const float* __restrict__ b_ih,
    const float* __restrict__ b_hh,
    const float* __restrict__ out_w,
    const float* __restrict__ out_b,
    const unsigned short* __restrict__ wpack,
    float* __restrict__ out)
{
    extern __shared__ unsigned char smem[];
    unsigned short* wlds  = (unsigned short*)smem;               // g=2 frags
    unsigned short* h_lds = (unsigned short*)(smem + HLDS_OFF);
    float*          obufw = (float*)(smem + OBUF_OFF);           // [2][8][32][2]

    const int tid  = threadIdx.x;
    const int lane = tid & 63;
    const int wv   = tid >> 6;
    const int l31  = lane & 31;
    const int l15  = lane & 15;
    const int qd   = lane >> 4;      // 0..3 (for 16x16 proj)
    const int hi   = lane >> 5;      // 0..1 (for 32x32 frags)
    const int rb   = blockIdx.x * 32;

    // ---- stage n-gate (g=2) frags into LDS (16 KB per wave) ----
#pragma unroll
    for (int kc = 0; kc < 16; ++kc) {
        int gfrag = (wv * 3 + 2) * 16 + kc;
        uint4 v = *(const uint4*)(wpack + gfrag * 512 + lane * 8);
        *(uint4*)(wlds + (wv * 16 + kc) * 512 + lane * 8) = v;
    }

    // ---- r,z-gate frags into registers (32 frags = 128 VGPRs) ----
    short8 wreg[32];
#pragma unroll
    for (int g = 0; g < 2; ++g)
#pragma unroll
        for (int kc = 0; kc < 16; ++kc)
            wreg[g * 16 + kc] = ((const short8*)wpack)[((wv * 3 + g) * 16 + kc) * 64 + lane];

    // ---- stage z tile (32x128 fp32 -> bf16) into h_lds ----
    {
        int row = tid >> 4;
        int seg = tid & 15;
        const float* zp = z + (size_t)(rb + row) * LATENT + seg * 8;
        unsigned int u[4];
#pragma unroll
        for (int j = 0; j < 4; ++j)
            u[j] = (unsigned int)f2bf(zp[2 * j]) | ((unsigned int)f2bf(zp[2 * j + 1]) << 16);
        *(uint4*)&h_lds[row * 264 + seg * 8] = make_uint4(u[0], u[1], u[2], u[3]);
    }

    // ---- per-lane constants: col = wv*32 + l31 ----
    float cbr, cbz, bin, bhn, fcb;
    {
        int col = wv * 32 + l31;
        cbr = b_ih[col]       + b_hh[col];
        cbz = b_ih[256 + col] + b_hh[256 + col];
        bin = b_ih[512 + col];
        bhn = b_hh[512 + col];
        fcb = fc_b[col];
    }
    float ob = (tid < 64) ? out_b[tid & 1] : 0.0f;

    // projection B-frag (16x16x32): B[k][n], k = wv*32 + qd*8 + j, n = l15 (0,1)
    short8 bproj;
    {
        int k0 = wv * 32 + qd * 8;
#pragma unroll
        for (int j = 0; j < 8; ++j) {
            float v = (l15 == 0) ? out_w[k0 + j] : ((l15 == 1) ? out_w[256 + k0 + j] : 0.0f);
            bproj[j] = (short)f2bf(v);
        }
    }

    __syncthreads();

    // ---- h0 = tanh(z @ fc_w^T + fc_b), 32x32x16 over K=128 ----
    floatx16 a0f;
#pragma unroll
    for (int i = 0; i < 16; ++i) a0f[i] = 0.0f;
#pragma unroll
    for (int kc = 0; kc < 8; ++kc) {
        short8 afr = *(const short8*)&h_lds[l31 * 264 + kc * 16 + hi * 8];
        short8 bfr = ((const short8*)wpack)[(size_t)(WHH_US / 8) + (wv * 8 + kc) * 64 + lane];
        a0f = __builtin_amdgcn_mfma_f32_32x32x16_bf16(afr, bfr, a0f, 0, 0, 0);
    }

    // master h fp32; C layout: col = wv*32 + l31, row = (i&3) + 8*(i>>2) + 4*hi
    float hm[16];
#pragma unroll
    for (int i = 0; i < 16; ++i) hm[i] = tanh_fast(a0f[i] + fcb);

    __syncthreads();   // all reads of z done
#pragma unroll
    for (int i = 0; i < 16; ++i) {
        int row = (i & 3) + 8 * (i >> 2) + 4 * hi;
        h_lds[row * 264 + wv * 32 + l31] = f2bf(hm[i]);
    }
    __syncthreads();

    // ---- 180 monolithic steps ----
    floatx4 pjA, pjB;
#pragma unroll 1
    for (int t = 0; t < T_SEQ; ++t) {
        const int p = t & 1;
        // ======== PHASE 1: MFMA on state t-1 (reads h_lds) ========
        floatx16 ar, az, an;
#pragma unroll
        for (int i = 0; i < 16; ++i) { ar[i] = cbr; az[i] = cbz; an[i] = bhn; }
#pragma unroll
        for (int kc = 0; kc < 16; ++kc) {
            short8 afr = *(const short8*)&h_lds[l31 * 264 + kc * 16 + hi * 8];
            ar = __builtin_amdgcn_mfma_f32_32x32x16_bf16(afr, wreg[kc],      ar, 0, 0, 0);
            az = __builtin_amdgcn_mfma_f32_32x32x16_bf16(afr, wreg[16 + kc], az, 0, 0, 0);
            short8 bn = *(const short8*)&wlds[(wv * 16 + kc) * 512 + lane * 8];
            an = __builtin_amdgcn_mfma_f32_32x32x16_bf16(afr, bn, an, 0, 0, 0);
        }
        // projection of state t-1 (out idx t-1), wave's own 32-col k-slice
        {
            short8 aA = *(const short8*)&h_lds[l15 * 264 + wv * 32 + qd * 8];
            short8 aB = *(const short8*)&h_lds[(16 + l15) * 264 + wv * 32 + qd * 8];
            pjA = (floatx4){0.f, 0.f, 0.f, 0.f};
            pjB = (floatx4){0.f, 0.f, 0.f, 0.f};
            pjA = __builtin_amdgcn_mfma_f32_16x16x32_bf16(aA, bproj, pjA, 0, 0, 0);
            pjB = __builtin_amdgcn_mfma_f32_16x16x32_bf16(aB, bproj, pjB, 0, 0, 0);
        }
        // flush ping-pong buffer written at step t-1 (proj of state t-2 = out idx t-2)
        if (t >= 2 && tid < 64) {
            int rl = tid >> 1, o = tid & 1;
            float s = ob;
#pragma unroll
            for (int w2 = 0; w2 < 8; ++w2) s += obufw[(p ^ 1) * 512 + w2 * 64 + rl * 2 + o];
            out[(size_t)(rb + rl) * (T_SEQ * 2) + (t - 2) * 2 + o] = s;
        }
        __syncthreads();   // all reads of state t-1 complete

        // ======== PHASE 2: gates -> state t, write h_lds, stash proj ========
#pragma unroll
        for (int i = 0; i < 16; ++i) {
            float gr = sigmoid_fast(ar[i]);
            float gz = sigmoid_fast(az[i]);
            float gn = tanh_fast(bin + gr * an[i]);
            float h  = gn + gz * (hm[i] - gn);     // (1-z)*n + z*h
            hm[i] = h;
            int row = (i & 3) + 8 * (i >> 2) + 4 * hi;
            h_lds[row * 264 + wv * 32 + l31] = f2bf(h);
        }
        if (t >= 1 && l15 < 2) {                   // per-wave partials, no atomics
#pragma unroll
            for (int r = 0; r < 4; ++r) {
                obufw[p * 512 + wv * 64 + (qd * 4 + r) * 2 + l15]        = pjA[r];
                obufw[p * 512 + wv * 64 + (16 + qd * 4 + r) * 2 + l15]   = pjB[r];
            }
        }
        __syncthreads();   // writes visible before next step's reads
    }

    // ---- epilogue: out idx 178 (stashed at t=179, buf p=1), then proj hs[179] ----
    if (tid < 64) {
        int rl = tid >> 1, o = tid & 1;
        float s = ob;
#pragma unroll
        for (int w2 = 0; w2 < 8; ++w2) s += obufw[512 + w2 * 64 + rl * 2 + o];
        out[(size_t)(rb + rl) * (T_SEQ * 2) + 178 * 2 + o] = s;
    }
    {   // proj of final state hs[179] (h_lds, visible after last barrier)
        short8 aA = *(const short8*)&h_lds[l15 * 264 + wv * 32 + qd * 8];
        short8 aB = *(const short8*)&h_lds[(16 + l15) * 264 + wv * 32 + qd * 8];
        floatx4 fA = (floatx4){0.f, 0.f, 0.f, 0.f};
        floatx4 fB = (floatx4){0.f, 0.f, 0.f, 0.f};
        fA = __builtin_amdgcn_mfma_f32_16x16x32_bf16(aA, bproj, fA, 0, 0, 0);
        fB = __builtin_amdgcn_mfma_f32_16x16x32_bf16(aB, bproj, fB, 0, 0, 0);
        if (l15 < 2)
#pragma unroll
            for (int r = 0; r < 4; ++r) {
                obufw[wv * 64 + (qd * 4 + r) * 2 + l15]      = fA[r];
                obufw[wv * 64 + (16 + qd * 4 + r) * 2 + l15] = fB[r];
            }
    }
    __syncthreads();
    if (tid < 64) {
        int rl = tid >> 1, o = tid & 1;
        float s = ob;
#pragma unroll
        for (int w2 = 0; w2 < 8; ++w2) s += obufw[w2 * 64 + rl * 2 + o];
        out[(size_t)(rb + rl) * (T_SEQ * 2) + 179 * 2 + o] = s;
    }
}

extern "C" void kernel_launch(void* const* d_in, const int* in_sizes, int n_in,
                              void* d_out, int out_size, void* d_ws, size_t ws_size,
                              hipStream_t stream) {
    const float* z     = (const float*)d_in[0];
    const float* fc_w  = (const float*)d_in[1];
    const float* fc_b  = (const float*)d_in[2];
    // d_in[3] = w_ih : unused (GRU input is all-zeros, gi = b_ih)
    const float* b_ih  = (const float*)d_in[4];
    const float* w_hh  = (const float*)d_in[5];
    const float* b_hh  = (const float*)d_in[6];
    const float* out_w = (const float*)d_in[7];
    const float* out_b = (const float*)d_in[8];
    float* out = (float*)d_out;
    unsigned short* wpack = (unsigned short*)d_ws;

    hipFuncSetAttribute((const void*)gru_main,
                        hipFuncAttributeMaxDynamicSharedMemorySize, SMEM_BYTES);

    pack_whh<<<96, 256, 0, stream>>>(w_hh, wpack);
    pack_fcw<<<16, 256, 0, stream>>>(fc_w, wpack + WHH_US);
    gru_main<<<256, 512, SMEM_BYTES, stream>>>(z, fc_b, b_ih, b_hh, out_w, out_b, wpack, out);
}